// Round 5
// baseline (836.723 us; speedup 1.0000x reference)
//
#include <hip/hip_runtime.h>
#include <stdint.h>
#include <stddef.h>

// ---------- types ----------
typedef __bf16 bf16x8 __attribute__((ext_vector_type(8)));
typedef float  f32x4  __attribute__((ext_vector_type(4)));

// float -> bf16 bits, round-to-nearest-even (finite inputs)
__device__ __forceinline__ unsigned short f2bf(float f) {
  unsigned int u = __builtin_bit_cast(unsigned int, f);
  u += 0x7fffu + ((u >> 16) & 1u);
  return (unsigned short)(u >> 16);
}

__device__ __forceinline__ void gld_lds16(const void* g, void* l) {
  __builtin_amdgcn_global_load_lds(
      (__attribute__((address_space(1))) void*)(g),
      (__attribute__((address_space(3))) void*)(l), 16, 0, 0);
}

#define BAR()     asm volatile("s_barrier" ::: "memory")
#define WAITVM(n) asm volatile("s_waitcnt vmcnt(" #n ")" ::: "memory")
#define SCHED0()  __builtin_amdgcn_sched_barrier(0)

// ---------- kernel 1: quotient-remainder fake-quant of x, emit bf16 ----------
__global__ __launch_bounds__(256) void quant_x_kernel(
    const float* __restrict__ x, unsigned short* __restrict__ xb, long long ngroups)
{
  const int lane = threadIdx.x & 63;
  const int wv   = threadIdx.x >> 6;
  long long g = (long long)blockIdx.x * 4 + wv;
  if (g >= ngroups) return;

  const float* xg = x + g * 128;
  float2 v = *reinterpret_cast<const float2*>(xg + lane * 2);

  float m = fmaxf(fabsf(v.x), fabsf(v.y));
  #pragma unroll
  for (int off = 32; off; off >>= 1) m = fmaxf(m, __shfl_xor(m, off));
  m = fmaxf(m, 1e-8f);

  float t = m / 7.0f;
  float base = t <= 2.f ? 2.f : t <= 4.f ? 4.f : t <= 8.f ? 8.f
             : t <= 16.f ? 16.f : t <= 32.f ? 32.f : 64.f;
  float inv_base = 1.0f / base;

  float q0 = fminf(fmaxf(rintf(v.x * inv_base), -7.f), 7.f);
  float q1 = fminf(fmaxf(rintf(v.y * inv_base), -7.f), 7.f);
  float r0 = v.x - base * q0;
  float r1 = v.y - base * q1;

  float mr = fmaxf(fabsf(r0), fabsf(r1));
  #pragma unroll
  for (int off = 32; off; off >>= 1) mr = fmaxf(mr, __shfl_xor(mr, off));
  mr = fmaxf(mr, 1e-8f);
  float scale_r = mr / 7.0f;

  float rd0 = fminf(fmaxf(rintf(r0 / scale_r), -8.f), 7.f) * scale_r;
  float rd1 = fminf(fmaxf(rintf(r1 / scale_r), -8.f), 7.f) * scale_r;

  float y0 = base * q0 + rd0;
  float y1 = base * q1 + rd1;

  unsigned int packed = (unsigned int)f2bf(y0) | ((unsigned int)f2bf(y1) << 16);
  *reinterpret_cast<unsigned int*>(xb + g * 128 + lane * 2) = packed;
}

// ---------- kernel 2: fp32 -> bf16 weight conversion ----------
__global__ __launch_bounds__(256) void cvt_w_kernel(
    const float* __restrict__ w, unsigned short* __restrict__ wb, long long n)
{
  long long i = ((long long)blockIdx.x * blockDim.x + threadIdx.x) * 8;
  if (i + 7 >= n) {
    if (i >= n) return;
    for (long long j = i; j < n; ++j) wb[j] = f2bf(w[j]);
    return;
  }
  float4 v0 = *reinterpret_cast<const float4*>(w + i);
  float4 v1 = *reinterpret_cast<const float4*>(w + i + 4);
  uint4 o;
  o.x = (unsigned)f2bf(v0.x) | ((unsigned)f2bf(v0.y) << 16);
  o.y = (unsigned)f2bf(v0.z) | ((unsigned)f2bf(v0.w) << 16);
  o.z = (unsigned)f2bf(v1.x) | ((unsigned)f2bf(v1.y) << 16);
  o.w = (unsigned)f2bf(v1.z) | ((unsigned)f2bf(v1.w) << 16);
  *reinterpret_cast<uint4*>(wb + i) = o;
}

// ---------- kernel 3: 256x256-tile pipelined 8-phase bf16 NT-GEMM + bias ----
// 8 waves (2M x 4N), BK=64, LDS ring = [dbuf][mat][half][128x64] (128 KiB).
// REGISTER-PIPELINED quadrants: each quadrant's ds_reads issue ONE PHASE EARLY
// so LDS service overlaps the previous quadrant's MFMA cluster:
//   P1: prefetch bh       ; MFMA Q1 (al x bl)
//   P2: prefetch ah       ; MFMA Q2 (al x bh)
//   P3: stage B(t+2)      ; MFMA Q3 (ah x bl) ; vmcnt ; BAR (boundary)
//   P4: prefetch al',bl'  ; stage A(t+2) ; MFMA Q4 (ah x bh)
// Boundary vmcnt(4) guarantees tile t+1's LDS data before P4's next-tile reads.
#define BM 256
#define BN 256
#define BK 64

#define MFMA16(a, b, c) __builtin_amdgcn_mfma_f32_16x16x32_bf16(a, b, c, 0, 0, 0)

__global__ __launch_bounds__(512, 2) void gemm256_bias(
    const unsigned short* __restrict__ A,   // [M][K] bf16 bits
    const unsigned short* __restrict__ B,   // [N][K] bf16 bits
    const float* __restrict__ bias,         // [N]
    float* __restrict__ C,                  // [M][N] fp32
    int M, int N, int K)
{
  __shared__ unsigned short lds[2][2][2][128 * 64];   // [dbuf][A/B][half] : 128 KiB

  const int tid  = threadIdx.x;
  const int lane = tid & 63;
  const int wid  = tid >> 6;       // 0..7
  const int wm   = wid >> 2;       // 0..1
  const int wn   = wid & 3;        // 0..3
  const int laneq = lane & 15;
  const int laneh = lane >> 4;
  const int lq7   = laneq & 7;

  // bijective XCD swizzle (grid % 8 == 0 for this shape)
  int nwg = gridDim.x;
  int bid = blockIdx.x;
  int wg = ((nwg & 7) == 0) ? ((bid & 7) * (nwg >> 3) + (bid >> 3)) : bid;

  const int ntn = N / BN;
  const int tm = wg / ntn;
  const int tn = wg % ntn;
  const size_t m0 = (size_t)tm * BM;
  const size_t n0 = (size_t)tn * BN;

  const int NT = K / BK;

  // swizzled 16B-slot offsets (elements) for ks=0,1
  const int s0 = ((0 * 4 + laneh) ^ lq7) * 8;
  const int s1 = ((1 * 4 + laneh) ^ lq7) * 8;

  f32x4 acc[8][4];
  #pragma unroll
  for (int i = 0; i < 8; i++)
    #pragma unroll
    for (int j = 0; j < 4; j++)
      acc[i][j] = (f32x4){0.f, 0.f, 0.f, 0.f};

  // stage one 128x64 half-tile (2 x global_load_lds per thread)
  auto stage = [&](int mat, int d, int h, int kt) {
    const unsigned short* gbase = (mat == 0)
        ? (A + (m0 + (size_t)h * 128) * (size_t)K)
        : (B + (n0 + (size_t)h * 128) * (size_t)K);
    const int k0 = kt * BK;
    #pragma unroll
    for (int l = 0; l < 2; ++l) {
      int c   = l * 512 + tid;          // chunk 0..1023
      int row = c >> 3;                 // 0..127
      int s   = (c & 7) ^ (row & 7);    // inverse-swizzled global slot
      gld_lds16(gbase + (size_t)row * K + k0 + s * 8,
                (char*)&lds[d][mat][h][0] + (l * 512 + wid * 64) * 16);
    }
  };

  // ---- prologue: stage tile0 + tile1 completely; wait only for tile0 ----
  stage(0, 0, 0, 0); stage(0, 0, 1, 0);
  stage(1, 0, 0, 0); stage(1, 0, 1, 0);
  stage(0, 1, 0, 1); stage(0, 1, 1, 1);
  stage(1, 1, 0, 1); stage(1, 1, 1, 1);
  WAITVM(8);          // tile0's 8 loads (oldest) arrived; tile1's may fly
  BAR();

  // fragment registers (all statically indexed)
  bf16x8 al[4][2], ah[4][2], bl[2][2], bh[2][2];

  // preload Q1 operands of tile 0
  {
    const unsigned short* As_ = &lds[0][0][wm][0];
    const unsigned short* Bs_ = &lds[0][1][wn >> 1][0];
    const int brow = (wn & 1) * 64;
    #pragma unroll
    for (int mi = 0; mi < 4; ++mi) {
      al[mi][0] = *(const bf16x8*)&As_[(mi * 16 + laneq) * 64 + s0];
      al[mi][1] = *(const bf16x8*)&As_[(mi * 16 + laneq) * 64 + s1];
    }
    #pragma unroll
    for (int nj = 0; nj < 2; ++nj) {
      bl[nj][0] = *(const bf16x8*)&Bs_[(brow + nj * 16 + laneq) * 64 + s0];
      bl[nj][1] = *(const bf16x8*)&Bs_[(brow + nj * 16 + laneq) * 64 + s1];
    }
  }

  for (int t = 0; t < NT; ++t) {
    const int d = t & 1;
    const unsigned short* As_ = &lds[d][0][wm][0];
    const unsigned short* Bs_ = &lds[d][1][wn >> 1][0];
    const unsigned short* An_ = &lds[d ^ 1][0][wm][0];      // next tile
    const unsigned short* Bn_ = &lds[d ^ 1][1][wn >> 1][0];
    const int brow = (wn & 1) * 64;

    // ---------- P1: prefetch bh ; MFMA Q1 (al x bl) ----------
    #pragma unroll
    for (int nj = 0; nj < 2; ++nj) {
      bh[nj][0] = *(const bf16x8*)&Bs_[(brow + 32 + nj * 16 + laneq) * 64 + s0];
      bh[nj][1] = *(const bf16x8*)&Bs_[(brow + 32 + nj * 16 + laneq) * 64 + s1];
    }
    BAR(); SCHED0();
    __builtin_amdgcn_s_setprio(1);
    #pragma unroll
    for (int mi = 0; mi < 4; ++mi)
      #pragma unroll
      for (int nj = 0; nj < 2; ++nj) {
        acc[mi][nj] = MFMA16(al[mi][0], bl[nj][0], acc[mi][nj]);
        acc[mi][nj] = MFMA16(al[mi][1], bl[nj][1], acc[mi][nj]);
      }
    __builtin_amdgcn_s_setprio(0);
    SCHED0(); BAR();

    // ---------- P2: prefetch ah ; MFMA Q2 (al x bh) ----------
    #pragma unroll
    for (int mi = 0; mi < 4; ++mi) {
      ah[mi][0] = *(const bf16x8*)&As_[(64 + mi * 16 + laneq) * 64 + s0];
      ah[mi][1] = *(const bf16x8*)&As_[(64 + mi * 16 + laneq) * 64 + s1];
    }
    BAR(); SCHED0();
    __builtin_amdgcn_s_setprio(1);
    #pragma unroll
    for (int mi = 0; mi < 4; ++mi)
      #pragma unroll
      for (int nj = 0; nj < 2; ++nj) {
        acc[mi][2 + nj] = MFMA16(al[mi][0], bh[nj][0], acc[mi][2 + nj]);
        acc[mi][2 + nj] = MFMA16(al[mi][1], bh[nj][1], acc[mi][2 + nj]);
      }
    __builtin_amdgcn_s_setprio(0);
    SCHED0(); BAR();

    // ---------- P3: stage B(t+2) ; MFMA Q3 (ah x bl) ; boundary vmcnt ------
    if (t + 2 < NT) { stage(1, d, 0, t + 2); stage(1, d, 1, t + 2); }
    BAR(); SCHED0();
    __builtin_amdgcn_s_setprio(1);
    #pragma unroll
    for (int mi = 0; mi < 4; ++mi)
      #pragma unroll
      for (int nj = 0; nj < 2; ++nj) {
        acc[4 + mi][nj] = MFMA16(ah[mi][0], bl[nj][0], acc[4 + mi][nj]);
        acc[4 + mi][nj] = MFMA16(ah[mi][1], bl[nj][1], acc[4 + mi][nj]);
      }
    __builtin_amdgcn_s_setprio(0);
    SCHED0();
    if (t == NT - 2)      { WAITVM(0); }
    else if (t < NT - 2)  { WAITVM(4); }
    BAR();

    // ---------- P4: prefetch al',bl' (tile t+1) ; stage A(t+2) ;
    //             MFMA Q4 (ah x bh) ----------
    if (t + 1 < NT) {
      #pragma unroll
      for (int mi = 0; mi < 4; ++mi) {
        al[mi][0] = *(const bf16x8*)&An_[(mi * 16 + laneq) * 64 + s0];
        al[mi][1] = *(const bf16x8*)&An_[(mi * 16 + laneq) * 64 + s1];
      }
      #pragma unroll
      for (int nj = 0; nj < 2; ++nj) {
        bl[nj][0] = *(const bf16x8*)&Bn_[(brow + nj * 16 + laneq) * 64 + s0];
        bl[nj][1] = *(const bf16x8*)&Bn_[(brow + nj * 16 + laneq) * 64 + s1];
      }
    }
    if (t + 2 < NT) { stage(0, d, 0, t + 2); stage(0, d, 1, t + 2); }
    BAR(); SCHED0();
    __builtin_amdgcn_s_setprio(1);
    #pragma unroll
    for (int mi = 0; mi < 4; ++mi)
      #pragma unroll
      for (int nj = 0; nj < 2; ++nj) {
        acc[4 + mi][2 + nj] = MFMA16(ah[mi][0], bh[nj][0], acc[4 + mi][2 + nj]);
        acc[4 + mi][2 + nj] = MFMA16(ah[mi][1], bh[nj][1], acc[4 + mi][2 + nj]);
      }
    __builtin_amdgcn_s_setprio(0);
    SCHED0(); BAR();
  }

  // ---- epilogue: C = acc + bias ----
  // C/D layout: col = lane&15, row = (lane>>4)*4 + reg
  #pragma unroll
  for (int nj = 0; nj < 4; ++nj) {
    int col = (int)n0 + wn * 64 + nj * 16 + laneq;
    float bv = bias[col];
    #pragma unroll
    for (int mi = 0; mi < 8; ++mi) {
      size_t row = m0 + wm * 128 + mi * 16 + laneh * 4;
      float* cp = C + row * (size_t)N + col;
      #pragma unroll
      for (int r = 0; r < 4; ++r)
        cp[(size_t)r * N] = acc[mi][nj][r] + bv;
    }
  }
}

// ---------- launcher ----------
extern "C" void kernel_launch(void* const* d_in, const int* in_sizes, int n_in,
                              void* d_out, int out_size, void* d_ws, size_t ws_size,
                              hipStream_t stream) {
  const float* x    = (const float*)d_in[0];
  const float* w    = (const float*)d_in[1];
  const float* bias = (const float*)d_in[2];
  float* out = (float*)d_out;

  const long long xN = in_sizes[0];          // M*K
  const long long wN = in_sizes[1];          // N*K
  const int N = in_sizes[2];
  const int K = (int)(wN / N);
  const int M = (int)(xN / K);

  unsigned short* xb = (unsigned short*)d_ws;          // M*K bf16
  unsigned short* wb = xb + xN;                        // N*K bf16

  long long ngroups = xN / 128;
  long long qblocks = (ngroups + 3) / 4;
  quant_x_kernel<<<(int)qblocks, 256, 0, stream>>>(x, xb, ngroups);

  long long cblocks = (wN + 2047) / 2048;
  cvt_w_kernel<<<(int)cblocks, 256, 0, stream>>>(w, wb, wN);

  int grid = (M / BM) * (N / BN);
  gemm256_bias<<<grid, 512, 0, stream>>>(xb, wb, bias, out, M, N, K);
}

// Round 6
// 805.910 us; speedup vs baseline: 1.0382x; 1.0382x over previous
//
#include <hip/hip_runtime.h>
#include <stdint.h>
#include <stddef.h>

// ---------- types ----------
typedef __bf16 bf16x8 __attribute__((ext_vector_type(8)));
typedef float  f32x4  __attribute__((ext_vector_type(4)));
typedef float  f32x2  __attribute__((ext_vector_type(2)));

// float -> bf16 bits, round-to-nearest-even (finite inputs)
__device__ __forceinline__ unsigned short f2bf(float f) {
  unsigned int u = __builtin_bit_cast(unsigned int, f);
  u += 0x7fffu + ((u >> 16) & 1u);
  return (unsigned short)(u >> 16);
}

__device__ __forceinline__ void gld_lds16(const void* g, void* l) {
  __builtin_amdgcn_global_load_lds(
      (__attribute__((address_space(1))) void*)(g),
      (__attribute__((address_space(3))) void*)(l), 16, 0, 0);
}

#define BAR()     asm volatile("s_barrier" ::: "memory")
#define WAITVM(n) asm volatile("s_waitcnt vmcnt(" #n ")" ::: "memory")

// ---------- kernel 1: quotient-remainder fake-quant of x, emit bf16 ----------
__global__ __launch_bounds__(256) void quant_x_kernel(
    const float* __restrict__ x, unsigned short* __restrict__ xb, long long ngroups)
{
  const int lane = threadIdx.x & 63;
  const int wv   = threadIdx.x >> 6;
  long long g = (long long)blockIdx.x * 4 + wv;
  if (g >= ngroups) return;

  const float* xg = x + g * 128;
  f32x2 v = __builtin_nontemporal_load(
      reinterpret_cast<const f32x2*>(xg + lane * 2));

  float m = fmaxf(fabsf(v[0]), fabsf(v[1]));
  #pragma unroll
  for (int off = 32; off; off >>= 1) m = fmaxf(m, __shfl_xor(m, off));
  m = fmaxf(m, 1e-8f);

  float t = m / 7.0f;
  float base = t <= 2.f ? 2.f : t <= 4.f ? 4.f : t <= 8.f ? 8.f
             : t <= 16.f ? 16.f : t <= 32.f ? 32.f : 64.f;
  float inv_base = 1.0f / base;

  float q0 = fminf(fmaxf(rintf(v[0] * inv_base), -7.f), 7.f);
  float q1 = fminf(fmaxf(rintf(v[1] * inv_base), -7.f), 7.f);
  float r0 = v[0] - base * q0;
  float r1 = v[1] - base * q1;

  float mr = fmaxf(fabsf(r0), fabsf(r1));
  #pragma unroll
  for (int off = 32; off; off >>= 1) mr = fmaxf(mr, __shfl_xor(mr, off));
  mr = fmaxf(mr, 1e-8f);
  float scale_r = mr / 7.0f;

  float rd0 = fminf(fmaxf(rintf(r0 / scale_r), -8.f), 7.f) * scale_r;
  float rd1 = fminf(fmaxf(rintf(r1 / scale_r), -8.f), 7.f) * scale_r;

  float y0 = base * q0 + rd0;
  float y1 = base * q1 + rd1;

  unsigned int packed = (unsigned int)f2bf(y0) | ((unsigned int)f2bf(y1) << 16);
  *reinterpret_cast<unsigned int*>(xb + g * 128 + lane * 2) = packed;
}

// ---------- kernel 2: fp32 -> bf16 weight conversion ----------
__global__ __launch_bounds__(256) void cvt_w_kernel(
    const float* __restrict__ w, unsigned short* __restrict__ wb, long long n)
{
  long long i = ((long long)blockIdx.x * blockDim.x + threadIdx.x) * 8;
  if (i + 7 >= n) {
    if (i >= n) return;
    for (long long j = i; j < n; ++j) wb[j] = f2bf(w[j]);
    return;
  }
  f32x4 v0 = __builtin_nontemporal_load(reinterpret_cast<const f32x4*>(w + i));
  f32x4 v1 = __builtin_nontemporal_load(reinterpret_cast<const f32x4*>(w + i + 4));
  uint4 o;
  o.x = (unsigned)f2bf(v0[0]) | ((unsigned)f2bf(v0[1]) << 16);
  o.y = (unsigned)f2bf(v0[2]) | ((unsigned)f2bf(v0[3]) << 16);
  o.z = (unsigned)f2bf(v1[0]) | ((unsigned)f2bf(v1[1]) << 16);
  o.w = (unsigned)f2bf(v1[2]) | ((unsigned)f2bf(v1[3]) << 16);
  *reinterpret_cast<uint4*>(wb + i) = o;
}

// ---------- kernel 3: 256x256-tile 8-phase bf16 NT-GEMM + bias ----------
// 8 waves (2M x 4N), BK=64, LDS ring = [dbuf][mat][half][128x64] (128 KiB).
// R4 deep-prefetch schedule (best so far) + L3-locality super-tile remap +
// non-temporal C stores (keep A/B panels resident in Infinity Cache).
#define BM 256
#define BN 256
#define BK 64

#define MFMA16(a, b, c) __builtin_amdgcn_mfma_f32_16x16x32_bf16(a, b, c, 0, 0, 0)

__global__ __launch_bounds__(512, 2) void gemm256_bias(
    const unsigned short* __restrict__ A,   // [M][K] bf16 bits
    const unsigned short* __restrict__ B,   // [N][K] bf16 bits
    const float* __restrict__ bias,         // [N]
    float* __restrict__ C,                  // [M][N] fp32
    int M, int N, int K)
{
  __shared__ unsigned short lds[2][2][2][128 * 64];   // [dbuf][A/B][half] : 128 KiB

  const int tid  = threadIdx.x;
  const int lane = tid & 63;
  const int wid  = tid >> 6;       // 0..7
  const int wm   = wid >> 2;       // 0..1
  const int wn   = wid & 3;        // 0..3
  const int laneq = lane & 15;
  const int laneh = lane >> 4;
  const int lq7   = laneq & 7;

  // ---- super-tile remap for L3 temporal locality ----
  // Launch-adjacent blocks (co-resident in time) cover a 16x16-tile super-tile
  // (~70 MB of A+B panels -> Infinity-Cache resident; panels re-fetched from
  // HBM only once per super-row/col: A x3, B x2 for this shape).
  const int ntm = M / BM;
  const int ntn = N / BN;
  int tm, tn;
  if ((ntm & 15) == 0) {
    int rem = blockIdx.x;
    int str = 0, stc = 0, w = 16;
    for (;;) {
      int w2 = (ntn - stc * 16 < 16) ? (ntn - stc * 16) : 16;
      int sz = 16 * w2;
      if (rem < sz) { w = w2; break; }
      rem -= sz;
      ++stc;
      if (stc * 16 >= ntn) { stc = 0; ++str; }
    }
    tm = str * 16 + rem / w;
    tn = stc * 16 + rem % w;
  } else {
    tm = (int)blockIdx.x / ntn;
    tn = (int)blockIdx.x % ntn;
  }
  const size_t m0 = (size_t)tm * BM;
  const size_t n0 = (size_t)tn * BN;

  const int NT = K / BK;

  // swizzled 16B-slot offsets (elements) for ks=0,1
  const int s0 = ((0 * 4 + laneh) ^ lq7) * 8;
  const int s1 = ((1 * 4 + laneh) ^ lq7) * 8;

  f32x4 acc[8][4];
  #pragma unroll
  for (int i = 0; i < 8; i++)
    #pragma unroll
    for (int j = 0; j < 4; j++)
      acc[i][j] = (f32x4){0.f, 0.f, 0.f, 0.f};

  // stage one 128x64 half-tile (2 x global_load_lds per thread)
  auto stage = [&](int mat, int d, int h, int kt) {
    const unsigned short* gbase = (mat == 0)
        ? (A + (m0 + (size_t)h * 128) * (size_t)K)
        : (B + (n0 + (size_t)h * 128) * (size_t)K);
    const int k0 = kt * BK;
    #pragma unroll
    for (int l = 0; l < 2; ++l) {
      int c   = l * 512 + tid;          // chunk 0..1023
      int row = c >> 3;                 // 0..127
      int s   = (c & 7) ^ (row & 7);    // inverse-swizzled global slot
      gld_lds16(gbase + (size_t)row * K + k0 + s * 8,
                (char*)&lds[d][mat][h][0] + (l * 512 + wid * 64) * 16);
    }
  };

  // ---- prologue: stage tile0 + tile1 completely; wait only for tile0 ----
  stage(0, 0, 0, 0); stage(0, 0, 1, 0);
  stage(1, 0, 0, 0); stage(1, 0, 1, 0);
  stage(0, 1, 0, 1); stage(0, 1, 1, 1);
  stage(1, 1, 0, 1); stage(1, 1, 1, 1);
  WAITVM(8);          // tile0's 8 loads (oldest) arrived; tile1's may fly
  BAR();

  for (int t = 0; t < NT; ++t) {
    const int d = t & 1;
    const unsigned short* As_ = &lds[d][0][wm][0];
    const unsigned short* Bs_ = &lds[d][1][wn >> 1][0];
    const int brow = (wn & 1) * 64;

    bf16x8 af[4][2], bl[2][2], bh[2][2];

    // ---------- phase 1: read A-lo + B-lo ----------
    #pragma unroll
    for (int mi = 0; mi < 4; ++mi) {
      af[mi][0] = *(const bf16x8*)&As_[(mi * 16 + laneq) * 64 + s0];
      af[mi][1] = *(const bf16x8*)&As_[(mi * 16 + laneq) * 64 + s1];
    }
    #pragma unroll
    for (int nj = 0; nj < 2; ++nj) {
      bl[nj][0] = *(const bf16x8*)&Bs_[(brow + nj * 16 + laneq) * 64 + s0];
      bl[nj][1] = *(const bf16x8*)&Bs_[(brow + nj * 16 + laneq) * 64 + s1];
    }
    BAR();
    __builtin_amdgcn_s_setprio(1);
    #pragma unroll
    for (int mi = 0; mi < 4; ++mi)
      #pragma unroll
      for (int nj = 0; nj < 2; ++nj) {
        acc[mi][nj] = MFMA16(af[mi][0], bl[nj][0], acc[mi][nj]);
        acc[mi][nj] = MFMA16(af[mi][1], bl[nj][1], acc[mi][nj]);
      }
    __builtin_amdgcn_s_setprio(0);
    BAR();

    // ---------- phase 2: read B-hi ----------
    #pragma unroll
    for (int nj = 0; nj < 2; ++nj) {
      bh[nj][0] = *(const bf16x8*)&Bs_[(brow + 32 + nj * 16 + laneq) * 64 + s0];
      bh[nj][1] = *(const bf16x8*)&Bs_[(brow + 32 + nj * 16 + laneq) * 64 + s1];
    }
    BAR();
    __builtin_amdgcn_s_setprio(1);
    #pragma unroll
    for (int mi = 0; mi < 4; ++mi)
      #pragma unroll
      for (int nj = 0; nj < 2; ++nj) {
        acc[mi][2 + nj] = MFMA16(af[mi][0], bh[nj][0], acc[mi][2 + nj]);
        acc[mi][2 + nj] = MFMA16(af[mi][1], bh[nj][1], acc[mi][2 + nj]);
      }
    __builtin_amdgcn_s_setprio(0);
    BAR();

    // ---------- phase 3: read A-hi ; stage B(t+2) both halves ----------
    #pragma unroll
    for (int mi = 0; mi < 4; ++mi) {
      af[mi][0] = *(const bf16x8*)&As_[(64 + mi * 16 + laneq) * 64 + s0];
      af[mi][1] = *(const bf16x8*)&As_[(64 + mi * 16 + laneq) * 64 + s1];
    }
    if (t + 2 < NT) { stage(1, d, 0, t + 2); stage(1, d, 1, t + 2); }
    BAR();
    __builtin_amdgcn_s_setprio(1);
    #pragma unroll
    for (int mi = 0; mi < 4; ++mi)
      #pragma unroll
      for (int nj = 0; nj < 2; ++nj) {
        acc[4 + mi][2 + nj] = MFMA16(af[mi][0], bh[nj][0], acc[4 + mi][2 + nj]);
        acc[4 + mi][2 + nj] = MFMA16(af[mi][1], bh[nj][1], acc[4 + mi][2 + nj]);
      }
    __builtin_amdgcn_s_setprio(0);
    BAR();

    // ---------- phase 4: stage A(t+2) both halves ; boundary vmcnt ----------
    if (t + 2 < NT) { stage(0, d, 0, t + 2); stage(0, d, 1, t + 2); }
    __builtin_amdgcn_s_setprio(1);
    #pragma unroll
    for (int mi = 0; mi < 4; ++mi)
      #pragma unroll
      for (int nj = 0; nj < 2; ++nj) {
        acc[4 + mi][nj] = MFMA16(af[mi][0], bl[nj][0], acc[4 + mi][nj]);
        acc[4 + mi][nj] = MFMA16(af[mi][1], bl[nj][1], acc[4 + mi][nj]);
      }
    __builtin_amdgcn_s_setprio(0);
    if (t == NT - 2)      { WAITVM(0); }
    else if (t < NT - 2)  { WAITVM(8); }
    BAR();
  }

  // ---- epilogue: C = acc + bias (non-temporal: don't churn L3) ----
  // C/D layout: col = lane&15, row = (lane>>4)*4 + reg
  #pragma unroll
  for (int nj = 0; nj < 4; ++nj) {
    int col = (int)n0 + wn * 64 + nj * 16 + laneq;
    float bv = bias[col];
    #pragma unroll
    for (int mi = 0; mi < 8; ++mi) {
      size_t row = m0 + wm * 128 + mi * 16 + laneh * 4;
      float* cp = C + row * (size_t)N + col;
      #pragma unroll
      for (int r = 0; r < 4; ++r)
        __builtin_nontemporal_store(acc[mi][nj][r] + bv, cp + (size_t)r * N);
    }
  }
}

// ---------- launcher ----------
extern "C" void kernel_launch(void* const* d_in, const int* in_sizes, int n_in,
                              void* d_out, int out_size, void* d_ws, size_t ws_size,
                              hipStream_t stream) {
  const float* x    = (const float*)d_in[0];
  const float* w    = (const float*)d_in[1];
  const float* bias = (const float*)d_in[2];
  float* out = (float*)d_out;

  const long long xN = in_sizes[0];          // M*K
  const long long wN = in_sizes[1];          // N*K
  const int N = in_sizes[2];
  const int K = (int)(wN / N);
  const int M = (int)(xN / K);

  unsigned short* xb = (unsigned short*)d_ws;          // M*K bf16
  unsigned short* wb = xb + xN;                        // N*K bf16

  long long ngroups = xN / 128;
  long long qblocks = (ngroups + 3) / 4;
  quant_x_kernel<<<(int)qblocks, 256, 0, stream>>>(x, xb, ngroups);

  long long cblocks = (wN + 2047) / 2048;
  cvt_w_kernel<<<(int)cblocks, 256, 0, stream>>>(w, wb, wN);

  int grid = (M / BM) * (N / BN);
  gemm256_bias<<<grid, 512, 0, stream>>>(xb, wb, bias, out, M, N, K);
}

// Round 7
// 803.403 us; speedup vs baseline: 1.0415x; 1.0031x over previous
//
#include <hip/hip_runtime.h>
#include <stdint.h>
#include <stddef.h>

// ---------- types ----------
typedef __bf16 bf16x8 __attribute__((ext_vector_type(8)));
typedef float  f32x4  __attribute__((ext_vector_type(4)));
typedef float  f32x2  __attribute__((ext_vector_type(2)));

// float -> bf16 bits, round-to-nearest-even (finite inputs)
__device__ __forceinline__ unsigned short f2bf(float f) {
  unsigned int u = __builtin_bit_cast(unsigned int, f);
  u += 0x7fffu + ((u >> 16) & 1u);
  return (unsigned short)(u >> 16);
}

__device__ __forceinline__ void gld_lds16(const void* g, void* l) {
  __builtin_amdgcn_global_load_lds(
      (__attribute__((address_space(1))) void*)(g),
      (__attribute__((address_space(3))) void*)(l), 16, 0, 0);
}

#define BAR()     asm volatile("s_barrier" ::: "memory")
#define WAITVM(n) asm volatile("s_waitcnt vmcnt(" #n ")" ::: "memory")

// ---------- kernel 1: quotient-remainder fake-quant of x, emit bf16 ----------
__global__ __launch_bounds__(256) void quant_x_kernel(
    const float* __restrict__ x, unsigned short* __restrict__ xb, long long ngroups)
{
  const int lane = threadIdx.x & 63;
  const int wv   = threadIdx.x >> 6;
  long long g = (long long)blockIdx.x * 4 + wv;
  if (g >= ngroups) return;

  const float* xg = x + g * 128;
  f32x2 v = __builtin_nontemporal_load(
      reinterpret_cast<const f32x2*>(xg + lane * 2));

  float m = fmaxf(fabsf(v[0]), fabsf(v[1]));
  #pragma unroll
  for (int off = 32; off; off >>= 1) m = fmaxf(m, __shfl_xor(m, off));
  m = fmaxf(m, 1e-8f);

  float t = m / 7.0f;
  float base = t <= 2.f ? 2.f : t <= 4.f ? 4.f : t <= 8.f ? 8.f
             : t <= 16.f ? 16.f : t <= 32.f ? 32.f : 64.f;
  float inv_base = 1.0f / base;

  float q0 = fminf(fmaxf(rintf(v[0] * inv_base), -7.f), 7.f);
  float q1 = fminf(fmaxf(rintf(v[1] * inv_base), -7.f), 7.f);
  float r0 = v[0] - base * q0;
  float r1 = v[1] - base * q1;

  float mr = fmaxf(fabsf(r0), fabsf(r1));
  #pragma unroll
  for (int off = 32; off; off >>= 1) mr = fmaxf(mr, __shfl_xor(mr, off));
  mr = fmaxf(mr, 1e-8f);
  float scale_r = mr / 7.0f;

  float rd0 = fminf(fmaxf(rintf(r0 / scale_r), -8.f), 7.f) * scale_r;
  float rd1 = fminf(fmaxf(rintf(r1 / scale_r), -8.f), 7.f) * scale_r;

  float y0 = base * q0 + rd0;
  float y1 = base * q1 + rd1;

  unsigned int packed = (unsigned int)f2bf(y0) | ((unsigned int)f2bf(y1) << 16);
  *reinterpret_cast<unsigned int*>(xb + g * 128 + lane * 2) = packed;
}

// ---------- kernel 2: fp32 -> bf16 weight conversion ----------
__global__ __launch_bounds__(256) void cvt_w_kernel(
    const float* __restrict__ w, unsigned short* __restrict__ wb, long long n)
{
  long long i = ((long long)blockIdx.x * blockDim.x + threadIdx.x) * 8;
  if (i + 7 >= n) {
    if (i >= n) return;
    for (long long j = i; j < n; ++j) wb[j] = f2bf(w[j]);
    return;
  }
  f32x4 v0 = __builtin_nontemporal_load(reinterpret_cast<const f32x4*>(w + i));
  f32x4 v1 = __builtin_nontemporal_load(reinterpret_cast<const f32x4*>(w + i + 4));
  uint4 o;
  o.x = (unsigned)f2bf(v0[0]) | ((unsigned)f2bf(v0[1]) << 16);
  o.y = (unsigned)f2bf(v0[2]) | ((unsigned)f2bf(v0[3]) << 16);
  o.z = (unsigned)f2bf(v1[0]) | ((unsigned)f2bf(v1[1]) << 16);
  o.w = (unsigned)f2bf(v1[2]) | ((unsigned)f2bf(v1[3]) << 16);
  *reinterpret_cast<uint4*>(wb + i) = o;
}

// ---------- kernel 3: 256x256-tile FREE-SCHEDULE bf16 NT-GEMM + bias ----------
// 8 waves (2M x 4N), BK=64, LDS dbuf (128 KiB).  Only TWO sync points per
// K-tile:  BAR_a (prev-tile reads all consumed) ; issue stage(t+1) ;
// WAITVM(8) ; BAR_b (this tile's LDS visible) ; then a barrier-FREE body of
// 24 ds_read_b128 + 64 MFMA per wave.  The 2 waves/SIMD drift/anti-phase so
// the LDS pipe and MFMA pipe overlap instead of serializing (the 8-phase
// lockstep measured as SUM(LDS,MFMA) per K-tile).
#define BM 256
#define BN 256
#define BK 64

#define MFMA16(a, b, c) __builtin_amdgcn_mfma_f32_16x16x32_bf16(a, b, c, 0, 0, 0)

__global__ __launch_bounds__(512, 2) void gemm256_bias(
    const unsigned short* __restrict__ A,   // [M][K] bf16 bits
    const unsigned short* __restrict__ B,   // [N][K] bf16 bits
    const float* __restrict__ bias,         // [N]
    float* __restrict__ C,                  // [M][N] fp32
    int M, int N, int K)
{
  __shared__ unsigned short lds[2][2][2][128 * 64];   // [dbuf][A/B][half] : 128 KiB

  const int tid  = threadIdx.x;
  const int lane = tid & 63;
  const int wid  = tid >> 6;       // 0..7
  const int wm   = wid >> 2;       // 0..1
  const int wn   = wid & 3;        // 0..3
  const int laneq = lane & 15;
  const int laneh = lane >> 4;
  const int lq7   = laneq & 7;

  // ---- super-tile remap for L3 temporal locality (R6: FETCH -23%) ----
  const int ntm = M / BM;
  const int ntn = N / BN;
  int tm, tn;
  if ((ntm & 15) == 0) {
    int rem = blockIdx.x;
    int str = 0, stc = 0, w = 16;
    for (;;) {
      int w2 = (ntn - stc * 16 < 16) ? (ntn - stc * 16) : 16;
      int sz = 16 * w2;
      if (rem < sz) { w = w2; break; }
      rem -= sz;
      ++stc;
      if (stc * 16 >= ntn) { stc = 0; ++str; }
    }
    tm = str * 16 + rem / w;
    tn = stc * 16 + rem % w;
  } else {
    tm = (int)blockIdx.x / ntn;
    tn = (int)blockIdx.x % ntn;
  }
  const size_t m0 = (size_t)tm * BM;
  const size_t n0 = (size_t)tn * BN;

  const int NT = K / BK;

  // swizzled 16B-slot offsets (elements) for ks=0,1
  const int s0 = ((0 * 4 + laneh) ^ lq7) * 8;
  const int s1 = ((1 * 4 + laneh) ^ lq7) * 8;

  f32x4 acc[8][4];
  #pragma unroll
  for (int i = 0; i < 8; i++)
    #pragma unroll
    for (int j = 0; j < 4; j++)
      acc[i][j] = (f32x4){0.f, 0.f, 0.f, 0.f};

  // stage one 128x64 half-tile (2 x global_load_lds per thread)
  auto stage = [&](int mat, int d, int h, int kt) {
    const unsigned short* gbase = (mat == 0)
        ? (A + (m0 + (size_t)h * 128) * (size_t)K)
        : (B + (n0 + (size_t)h * 128) * (size_t)K);
    const int k0 = kt * BK;
    #pragma unroll
    for (int l = 0; l < 2; ++l) {
      int c   = l * 512 + tid;          // chunk 0..1023
      int row = c >> 3;                 // 0..127
      int s   = (c & 7) ^ (row & 7);    // inverse-swizzled global slot
      gld_lds16(gbase + (size_t)row * K + k0 + s * 8,
                (char*)&lds[d][mat][h][0] + (l * 512 + wid * 64) * 16);
    }
  };

  // ---- prologue: stage tile 0 only ----
  stage(0, 0, 0, 0); stage(0, 0, 1, 0);
  stage(1, 0, 0, 0); stage(1, 0, 1, 0);

  for (int t = 0; t < NT; ++t) {
    const int d = t & 1;

    // ---- sync block: 2 barriers + counted vmcnt per K-tile ----
    BAR();                     // all waves consumed tile t-1's reads
    if (t + 1 < NT) {
      const int dn = d ^ 1;
      stage(0, dn, 0, t + 1); stage(0, dn, 1, t + 1);
      stage(1, dn, 0, t + 1); stage(1, dn, 1, t + 1);
      WAITVM(8);               // tile t's 8 loads (older) landed; t+1's fly
    } else {
      WAITVM(0);
    }
    BAR();                     // tile t's LDS visible to all waves

    // ---- barrier-free body: compiler/wave-drift overlaps LDS & MFMA ----
    const unsigned short* As_ = &lds[d][0][wm][0];
    const unsigned short* Bs_ = &lds[d][1][wn >> 1][0];
    const int brow = (wn & 1) * 64;

    bf16x8 al[4][2], ah[4][2], bl[2][2], bh[2][2];

    #pragma unroll
    for (int mi = 0; mi < 4; ++mi) {
      al[mi][0] = *(const bf16x8*)&As_[(mi * 16 + laneq) * 64 + s0];
      al[mi][1] = *(const bf16x8*)&As_[(mi * 16 + laneq) * 64 + s1];
    }
    #pragma unroll
    for (int nj = 0; nj < 2; ++nj) {
      bl[nj][0] = *(const bf16x8*)&Bs_[(brow + nj * 16 + laneq) * 64 + s0];
      bl[nj][1] = *(const bf16x8*)&Bs_[(brow + nj * 16 + laneq) * 64 + s1];
    }
    #pragma unroll
    for (int mi = 0; mi < 4; ++mi)
      #pragma unroll
      for (int nj = 0; nj < 2; ++nj) {
        acc[mi][nj] = MFMA16(al[mi][0], bl[nj][0], acc[mi][nj]);
        acc[mi][nj] = MFMA16(al[mi][1], bl[nj][1], acc[mi][nj]);
      }

    #pragma unroll
    for (int nj = 0; nj < 2; ++nj) {
      bh[nj][0] = *(const bf16x8*)&Bs_[(brow + 32 + nj * 16 + laneq) * 64 + s0];
      bh[nj][1] = *(const bf16x8*)&Bs_[(brow + 32 + nj * 16 + laneq) * 64 + s1];
    }
    #pragma unroll
    for (int mi = 0; mi < 4; ++mi)
      #pragma unroll
      for (int nj = 0; nj < 2; ++nj) {
        acc[mi][2 + nj] = MFMA16(al[mi][0], bh[nj][0], acc[mi][2 + nj]);
        acc[mi][2 + nj] = MFMA16(al[mi][1], bh[nj][1], acc[mi][2 + nj]);
      }

    #pragma unroll
    for (int mi = 0; mi < 4; ++mi) {
      ah[mi][0] = *(const bf16x8*)&As_[(64 + mi * 16 + laneq) * 64 + s0];
      ah[mi][1] = *(const bf16x8*)&As_[(64 + mi * 16 + laneq) * 64 + s1];
    }
    #pragma unroll
    for (int mi = 0; mi < 4; ++mi)
      #pragma unroll
      for (int nj = 0; nj < 2; ++nj) {
        acc[4 + mi][2 + nj] = MFMA16(ah[mi][0], bh[nj][0], acc[4 + mi][2 + nj]);
        acc[4 + mi][2 + nj] = MFMA16(ah[mi][1], bh[nj][1], acc[4 + mi][2 + nj]);
      }
    #pragma unroll
    for (int mi = 0; mi < 4; ++mi)
      #pragma unroll
      for (int nj = 0; nj < 2; ++nj) {
        acc[4 + mi][nj] = MFMA16(ah[mi][0], bl[nj][0], acc[4 + mi][nj]);
        acc[4 + mi][nj] = MFMA16(ah[mi][1], bl[nj][1], acc[4 + mi][nj]);
      }
  }

  // ---- epilogue: C = acc + bias (non-temporal: don't churn L3) ----
  // C/D layout: col = lane&15, row = (lane>>4)*4 + reg
  #pragma unroll
  for (int nj = 0; nj < 4; ++nj) {
    int col = (int)n0 + wn * 64 + nj * 16 + laneq;
    float bv = bias[col];
    #pragma unroll
    for (int mi = 0; mi < 8; ++mi) {
      size_t row = m0 + wm * 128 + mi * 16 + laneh * 4;
      float* cp = C + row * (size_t)N + col;
      #pragma unroll
      for (int r = 0; r < 4; ++r)
        __builtin_nontemporal_store(acc[mi][nj][r] + bv, cp + (size_t)r * N);
    }
  }
}

// ---------- launcher ----------
extern "C" void kernel_launch(void* const* d_in, const int* in_sizes, int n_in,
                              void* d_out, int out_size, void* d_ws, size_t ws_size,
                              hipStream_t stream) {
  const float* x    = (const float*)d_in[0];
  const float* w    = (const float*)d_in[1];
  const float* bias = (const float*)d_in[2];
  float* out = (float*)d_out;

  const long long xN = in_sizes[0];          // M*K
  const long long wN = in_sizes[1];          // N*K
  const int N = in_sizes[2];
  const int K = (int)(wN / N);
  const int M = (int)(xN / K);

  unsigned short* xb = (unsigned short*)d_ws;          // M*K bf16
  unsigned short* wb = xb + xN;                        // N*K bf16

  long long ngroups = xN / 128;
  long long qblocks = (ngroups + 3) / 4;
  quant_x_kernel<<<(int)qblocks, 256, 0, stream>>>(x, xb, ngroups);

  long long cblocks = (wN + 2047) / 2048;
  cvt_w_kernel<<<(int)cblocks, 256, 0, stream>>>(w, wb, wN);

  int grid = (M / BM) * (N / BN);
  gemm256_bias<<<grid, 512, 0, stream>>>(xb, wb, bias, out, M, N, K);
}

// Round 9
// 782.221 us; speedup vs baseline: 1.0697x; 1.0271x over previous
//
#include <hip/hip_runtime.h>
#include <stdint.h>
#include <stddef.h>

// ---------- types ----------
typedef __bf16 bf16x8 __attribute__((ext_vector_type(8)));
typedef float  f32x4  __attribute__((ext_vector_type(4)));
typedef float  f32x2  __attribute__((ext_vector_type(2)));

// float -> bf16 bits, round-to-nearest-even (finite inputs)
__device__ __forceinline__ unsigned short f2bf(float f) {
  unsigned int u = __builtin_bit_cast(unsigned int, f);
  u += 0x7fffu + ((u >> 16) & 1u);
  return (unsigned short)(u >> 16);
}

__device__ __forceinline__ void gld_lds16(const void* g, void* l) {
  __builtin_amdgcn_global_load_lds(
      (__attribute__((address_space(1))) void*)(g),
      (__attribute__((address_space(3))) void*)(l), 16, 0, 0);
}

#define BAR()     asm volatile("s_barrier" ::: "memory")
#define WAITVM(n) asm volatile("s_waitcnt vmcnt(" #n ")" ::: "memory")
#define WAITLG0() asm volatile("s_waitcnt lgkmcnt(0)" ::: "memory")
#define SCHED0()  __builtin_amdgcn_sched_barrier(0)

// ---------- kernel 1: quotient-remainder fake-quant of x, emit bf16 ----------
__global__ __launch_bounds__(256) void quant_x_kernel(
    const float* __restrict__ x, unsigned short* __restrict__ xb, long long ngroups)
{
  const int lane = threadIdx.x & 63;
  const int wv   = threadIdx.x >> 6;
  long long g = (long long)blockIdx.x * 4 + wv;
  if (g >= ngroups) return;

  const float* xg = x + g * 128;
  f32x2 v = __builtin_nontemporal_load(
      reinterpret_cast<const f32x2*>(xg + lane * 2));

  float m = fmaxf(fabsf(v[0]), fabsf(v[1]));
  #pragma unroll
  for (int off = 32; off; off >>= 1) m = fmaxf(m, __shfl_xor(m, off));
  m = fmaxf(m, 1e-8f);

  float t = m / 7.0f;
  float base = t <= 2.f ? 2.f : t <= 4.f ? 4.f : t <= 8.f ? 8.f
             : t <= 16.f ? 16.f : t <= 32.f ? 32.f : 64.f;
  float inv_base = 1.0f / base;

  float q0 = fminf(fmaxf(rintf(v[0] * inv_base), -7.f), 7.f);
  float q1 = fminf(fmaxf(rintf(v[1] * inv_base), -7.f), 7.f);
  float r0 = v[0] - base * q0;
  float r1 = v[1] - base * q1;

  float mr = fmaxf(fabsf(r0), fabsf(r1));
  #pragma unroll
  for (int off = 32; off; off >>= 1) mr = fmaxf(mr, __shfl_xor(mr, off));
  mr = fmaxf(mr, 1e-8f);
  float scale_r = mr / 7.0f;

  float rd0 = fminf(fmaxf(rintf(r0 / scale_r), -8.f), 7.f) * scale_r;
  float rd1 = fminf(fmaxf(rintf(r1 / scale_r), -8.f), 7.f) * scale_r;

  float y0 = base * q0 + rd0;
  float y1 = base * q1 + rd1;

  unsigned int packed = (unsigned int)f2bf(y0) | ((unsigned int)f2bf(y1) << 16);
  *reinterpret_cast<unsigned int*>(xb + g * 128 + lane * 2) = packed;
}

// ---------- kernel 2: fp32 -> bf16 weight conversion ----------
__global__ __launch_bounds__(256) void cvt_w_kernel(
    const float* __restrict__ w, unsigned short* __restrict__ wb, long long n)
{
  long long i = ((long long)blockIdx.x * blockDim.x + threadIdx.x) * 8;
  if (i + 7 >= n) {
    if (i >= n) return;
    for (long long j = i; j < n; ++j) wb[j] = f2bf(w[j]);
    return;
  }
  f32x4 v0 = __builtin_nontemporal_load(reinterpret_cast<const f32x4*>(w + i));
  f32x4 v1 = __builtin_nontemporal_load(reinterpret_cast<const f32x4*>(w + i + 4));
  uint4 o;
  o.x = (unsigned)f2bf(v0[0]) | ((unsigned)f2bf(v0[1]) << 16);
  o.y = (unsigned)f2bf(v0[2]) | ((unsigned)f2bf(v0[3]) << 16);
  o.z = (unsigned)f2bf(v1[0]) | ((unsigned)f2bf(v1[1]) << 16);
  o.w = (unsigned)f2bf(v1[2]) | ((unsigned)f2bf(v1[3]) << 16);
  *reinterpret_cast<uint4*>(wb + i) = o;
}

// ---------- kernel 3: 256x256-tile single-barrier-phase bf16 NT-GEMM + bias --
// 8 waves (2M x 4N), BK=64, LDS dbuf (128 KiB).
// Phase = [reads(next operands) ... BAR ... stage(after BAR) ... lgkm0 ...
//          setprio(1) MFMA x16 setprio(0)]  -- NO trailing barrier, so a wave
// finishing MFMA early issues its next ds_reads while stragglers MFMA.
// R8 BUGFIX: tile t+2 lands in buffer (t+2)&1 == t&1 == d (the CURRENT buffer,
// whose data is provably in registers by BAR3/BAR4), NOT d^1 (which holds the
// not-yet-consumed tile t+1).  Race-freedom: a wave arrives at BAR3 only after
// P2's lgkmcnt(0) (bl,bh in regs) and at BAR4 only after P3's lgkmcnt(0)
// (ah in regs), so post-barrier stage writes never clobber unsecured data.
#define BM 256
#define BN 256
#define BK 64

#define MFMA16(a, b, c) __builtin_amdgcn_mfma_f32_16x16x32_bf16(a, b, c, 0, 0, 0)

__global__ __launch_bounds__(512, 2) void gemm256_bias(
    const unsigned short* __restrict__ A,   // [M][K] bf16 bits
    const unsigned short* __restrict__ B,   // [N][K] bf16 bits
    const float* __restrict__ bias,         // [N]
    float* __restrict__ C,                  // [M][N] fp32
    int M, int N, int K)
{
  __shared__ unsigned short lds[2][2][2][128 * 64];   // [dbuf][A/B][half] : 128 KiB

  const int tid  = threadIdx.x;
  const int lane = tid & 63;
  const int wid  = tid >> 6;       // 0..7
  const int wm   = wid >> 2;       // 0..1
  const int wn   = wid & 3;        // 0..3
  const int laneq = lane & 15;
  const int laneh = lane >> 4;
  const int lq7   = laneq & 7;

  // ---- super-tile remap for L3 temporal locality (R6: FETCH -23%) ----
  const int ntm = M / BM;
  const int ntn = N / BN;
  int tm, tn;
  if ((ntm & 15) == 0) {
    int rem = blockIdx.x;
    int str = 0, stc = 0, w = 16;
    for (;;) {
      int w2 = (ntn - stc * 16 < 16) ? (ntn - stc * 16) : 16;
      int sz = 16 * w2;
      if (rem < sz) { w = w2; break; }
      rem -= sz;
      ++stc;
      if (stc * 16 >= ntn) { stc = 0; ++str; }
    }
    tm = str * 16 + rem / w;
    tn = stc * 16 + rem % w;
  } else {
    tm = (int)blockIdx.x / ntn;
    tn = (int)blockIdx.x % ntn;
  }
  const size_t m0 = (size_t)tm * BM;
  const size_t n0 = (size_t)tn * BN;

  const int NT = K / BK;

  // swizzled 16B-slot indices for ks=0,1
  const int ss0 = (laneh ^ lq7);        // slot 0..7
  const int ss1 = ((4 + laneh) ^ lq7);

  // per-thread LDS read base offsets (bytes)
  const char* ldsb = (const char*)&lds[0][0][0][0];
  const int aOff = wm * 16384 + laneq * 128;
  const int bOff = 32768 + (wn >> 1) * 16384 + ((wn & 1) * 64 + laneq) * 128;

  // per-thread staging source pointers (computed once)
  const int c0 = tid, c1 = 512 + tid;
  const int r0 = c0 >> 3, sl0 = (c0 & 7) ^ (r0 & 7);
  const int r1 = c1 >> 3, sl1 = (c1 & 7) ^ (r1 & 7);
  const unsigned short* gA0 = A + (m0 + r0) * (size_t)K + sl0 * 8;
  const unsigned short* gA1 = A + (m0 + r1) * (size_t)K + sl1 * 8;
  const unsigned short* gB0 = B + (n0 + r0) * (size_t)K + sl0 * 8;
  const unsigned short* gB1 = B + (n0 + r1) * (size_t)K + sl1 * 8;
  const size_t hstep = (size_t)128 * K;   // +128 rows

  // per-thread staging LDS dest bases (bytes): + mat*32768 + h*16384 + l*8192
  char* dst0 = (char*)ldsb + wid * 1024;           // dbuf 0
  char* dst1 = dst0 + 65536;                       // dbuf 1

  f32x4 acc[8][4];
  #pragma unroll
  for (int i = 0; i < 8; i++)
    #pragma unroll
    for (int j = 0; j < 4; j++)
      acc[i][j] = (f32x4){0.f, 0.f, 0.f, 0.f};

  // stage one 128x64 half-tile: mat(0=A,1=B), half h, K-tile kt, into dstD
  #define STAGE(mat, h, kt, dstD)                                            \
    do {                                                                     \
      const unsigned short* g0_ = (mat == 0) ? gA0 : gB0;                    \
      const unsigned short* g1_ = (mat == 0) ? gA1 : gB1;                    \
      gld_lds16(g0_ + (size_t)(h) * hstep + (size_t)(kt) * 64,               \
                (dstD) + (mat) * 32768 + (h) * 16384);                       \
      gld_lds16(g1_ + (size_t)(h) * hstep + (size_t)(kt) * 64,               \
                (dstD) + (mat) * 32768 + (h) * 16384 + 8192);                \
    } while (0)

  // ---- prologue: stage tile0 (dbuf0) + tile1 (dbuf1); wait tile0 ----
  STAGE(0, 0, 0, dst0); STAGE(0, 1, 0, dst0);
  STAGE(1, 0, 0, dst0); STAGE(1, 1, 0, dst0);
  STAGE(0, 0, 1, dst1); STAGE(0, 1, 1, dst1);
  STAGE(1, 0, 1, dst1); STAGE(1, 1, 1, dst1);
  WAITVM(8);
  BAR();

  bf16x8 al[4][2], ah[4][2], bl[2][2], bh[2][2];

  for (int t = 0; t < NT; ++t) {
    const int d = t & 1;
    const char* aS0 = ldsb + (d << 16) + aOff + ss0 * 16;
    const char* aS1 = ldsb + (d << 16) + aOff + ss1 * 16;
    const char* bS0 = ldsb + (d << 16) + bOff + ss0 * 16;
    const char* bS1 = ldsb + (d << 16) + bOff + ss1 * 16;
    char* dstn = d ? dst1 : dst0;     // FIX: tile t+2 -> buffer (t+2)&1 == d

    // ---- P1: reads al,bl ; BAR ; MFMA Q1 ----
    #pragma unroll
    for (int mi = 0; mi < 4; ++mi) {
      al[mi][0] = *(const bf16x8*)(aS0 + mi * 2048);
      al[mi][1] = *(const bf16x8*)(aS1 + mi * 2048);
    }
    #pragma unroll
    for (int nj = 0; nj < 2; ++nj) {
      bl[nj][0] = *(const bf16x8*)(bS0 + nj * 2048);
      bl[nj][1] = *(const bf16x8*)(bS1 + nj * 2048);
    }
    BAR();
    WAITLG0(); SCHED0();
    __builtin_amdgcn_s_setprio(1);
    #pragma unroll
    for (int mi = 0; mi < 4; ++mi)
      #pragma unroll
      for (int nj = 0; nj < 2; ++nj) {
        acc[mi][nj] = MFMA16(al[mi][0], bl[nj][0], acc[mi][nj]);
        acc[mi][nj] = MFMA16(al[mi][1], bl[nj][1], acc[mi][nj]);
      }
    __builtin_amdgcn_s_setprio(0);

    // ---- P2: reads bh ; BAR ; MFMA Q2 ----
    #pragma unroll
    for (int nj = 0; nj < 2; ++nj) {
      bh[nj][0] = *(const bf16x8*)(bS0 + 4096 + nj * 2048);
      bh[nj][1] = *(const bf16x8*)(bS1 + 4096 + nj * 2048);
    }
    BAR();
    WAITLG0(); SCHED0();
    __builtin_amdgcn_s_setprio(1);
    #pragma unroll
    for (int mi = 0; mi < 4; ++mi)
      #pragma unroll
      for (int nj = 0; nj < 2; ++nj) {
        acc[mi][2 + nj] = MFMA16(al[mi][0], bh[nj][0], acc[mi][2 + nj]);
        acc[mi][2 + nj] = MFMA16(al[mi][1], bh[nj][1], acc[mi][2 + nj]);
      }
    __builtin_amdgcn_s_setprio(0);

    // ---- P3: reads ah ; BAR ; stage B(t+2) ; MFMA Q3 ----
    #pragma unroll
    for (int mi = 0; mi < 4; ++mi) {
      ah[mi][0] = *(const bf16x8*)(aS0 + 8192 + mi * 2048);
      ah[mi][1] = *(const bf16x8*)(aS1 + 8192 + mi * 2048);
    }
    BAR();
    if (t + 2 < NT) { STAGE(1, 0, t + 2, dstn); STAGE(1, 1, t + 2, dstn); }
    WAITLG0(); SCHED0();
    __builtin_amdgcn_s_setprio(1);
    #pragma unroll
    for (int mi = 0; mi < 4; ++mi)
      #pragma unroll
      for (int nj = 0; nj < 2; ++nj) {
        acc[4 + mi][2 + nj] = MFMA16(ah[mi][0], bh[nj][0], acc[4 + mi][2 + nj]);
        acc[4 + mi][2 + nj] = MFMA16(ah[mi][1], bh[nj][1], acc[4 + mi][2 + nj]);
      }
    __builtin_amdgcn_s_setprio(0);

    // ---- P4: BAR ; stage A(t+2) ; MFMA Q4 ; boundary vmcnt+BAR ----
    BAR();
    if (t + 2 < NT) { STAGE(0, 0, t + 2, dstn); STAGE(0, 1, t + 2, dstn); }
    SCHED0();
    __builtin_amdgcn_s_setprio(1);
    #pragma unroll
    for (int mi = 0; mi < 4; ++mi)
      #pragma unroll
      for (int nj = 0; nj < 2; ++nj) {
        acc[4 + mi][nj] = MFMA16(ah[mi][0], bl[nj][0], acc[4 + mi][nj]);
        acc[4 + mi][nj] = MFMA16(ah[mi][1], bl[nj][1], acc[4 + mi][nj]);
      }
    __builtin_amdgcn_s_setprio(0);
    if (t == NT - 2)      { WAITVM(0); }
    else if (t < NT - 2)  { WAITVM(8); }
    BAR();
  }
  #undef STAGE

  // ---- epilogue: C = acc + bias (non-temporal: don't churn L3) ----
  // C/D layout: col = lane&15, row = (lane>>4)*4 + reg
  #pragma unroll
  for (int nj = 0; nj < 4; ++nj) {
    int col = (int)n0 + wn * 64 + nj * 16 + laneq;
    float bv = bias[col];
    #pragma unroll
    for (int mi = 0; mi < 8; ++mi) {
      size_t row = m0 + wm * 128 + mi * 16 + laneh * 4;
      float* cp = C + row * (size_t)N + col;
      #pragma unroll
      for (int r = 0; r < 4; ++r)
        __builtin_nontemporal_store(acc[mi][nj][r] + bv, cp + (size_t)r * N);
    }
  }
}

// ---------- launcher ----------
extern "C" void kernel_launch(void* const* d_in, const int* in_sizes, int n_in,
                              void* d_out, int out_size, void* d_ws, size_t ws_size,
                              hipStream_t stream) {
  const float* x    = (const float*)d_in[0];
  const float* w    = (const float*)d_in[1];
  const float* bias = (const float*)d_in[2];
  float* out = (float*)d_out;

  const long long xN = in_sizes[0];          // M*K
  const long long wN = in_sizes[1];          // N*K
  const int N = in_sizes[2];
  const int K = (int)(wN / N);
  const int M = (int)(xN / K);

  unsigned short* xb = (unsigned short*)d_ws;          // M*K bf16
  unsigned short* wb = xb + xN;                        // N*K bf16

  long long ngroups = xN / 128;
  long long qblocks = (ngroups + 3) / 4;
  quant_x_kernel<<<(int)qblocks, 256, 0, stream>>>(x, xb, ngroups);

  long long cblocks = (wN + 2047) / 2048;
  cvt_w_kernel<<<(int)cblocks, 256, 0, stream>>>(w, wb, wN);

  int grid = (M / BM) * (N / BN);
  gemm256_bias<<<grid, 512, 0, stream>>>(xb, wb, bias, out, M, N, K);
}

// Round 10
// 763.290 us; speedup vs baseline: 1.0962x; 1.0248x over previous
//
#include <hip/hip_runtime.h>
#include <stdint.h>
#include <stddef.h>

// ---------- types ----------
typedef __bf16 bf16x8 __attribute__((ext_vector_type(8)));
typedef float  f32x4  __attribute__((ext_vector_type(4)));
typedef float  f32x2  __attribute__((ext_vector_type(2)));

// float -> bf16 bits, round-to-nearest-even (finite inputs)
__device__ __forceinline__ unsigned short f2bf(float f) {
  unsigned int u = __builtin_bit_cast(unsigned int, f);
  u += 0x7fffu + ((u >> 16) & 1u);
  return (unsigned short)(u >> 16);
}

__device__ __forceinline__ void gld_lds16(const void* g, void* l) {
  __builtin_amdgcn_global_load_lds(
      (__attribute__((address_space(1))) void*)(g),
      (__attribute__((address_space(3))) void*)(l), 16, 0, 0);
}

#define BAR()     asm volatile("s_barrier" ::: "memory")
#define WAITVM(n) asm volatile("s_waitcnt vmcnt(" #n ")" ::: "memory")
#define SCHED0()  __builtin_amdgcn_sched_barrier(0)

// ---------- kernel 1: quotient-remainder fake-quant of x, emit bf16 ----------
__global__ __launch_bounds__(256) void quant_x_kernel(
    const float* __restrict__ x, unsigned short* __restrict__ xb, long long ngroups)
{
  const int lane = threadIdx.x & 63;
  const int wv   = threadIdx.x >> 6;
  long long g = (long long)blockIdx.x * 4 + wv;
  if (g >= ngroups) return;

  const float* xg = x + g * 128;
  f32x2 v = __builtin_nontemporal_load(
      reinterpret_cast<const f32x2*>(xg + lane * 2));

  float m = fmaxf(fabsf(v[0]), fabsf(v[1]));
  #pragma unroll
  for (int off = 32; off; off >>= 1) m = fmaxf(m, __shfl_xor(m, off));
  m = fmaxf(m, 1e-8f);

  float t = m / 7.0f;
  float base = t <= 2.f ? 2.f : t <= 4.f ? 4.f : t <= 8.f ? 8.f
             : t <= 16.f ? 16.f : t <= 32.f ? 32.f : 64.f;
  float inv_base = 1.0f / base;

  float q0 = fminf(fmaxf(rintf(v[0] * inv_base), -7.f), 7.f);
  float q1 = fminf(fmaxf(rintf(v[1] * inv_base), -7.f), 7.f);
  float r0 = v[0] - base * q0;
  float r1 = v[1] - base * q1;

  float mr = fmaxf(fabsf(r0), fabsf(r1));
  #pragma unroll
  for (int off = 32; off; off >>= 1) mr = fmaxf(mr, __shfl_xor(mr, off));
  mr = fmaxf(mr, 1e-8f);
  float scale_r = mr / 7.0f;

  float rd0 = fminf(fmaxf(rintf(r0 / scale_r), -8.f), 7.f) * scale_r;
  float rd1 = fminf(fmaxf(rintf(r1 / scale_r), -8.f), 7.f) * scale_r;

  float y0 = base * q0 + rd0;
  float y1 = base * q1 + rd1;

  unsigned int packed = (unsigned int)f2bf(y0) | ((unsigned int)f2bf(y1) << 16);
  *reinterpret_cast<unsigned int*>(xb + g * 128 + lane * 2) = packed;
}

// ---------- kernel 2: fp32 -> bf16 weight conversion ----------
__global__ __launch_bounds__(256) void cvt_w_kernel(
    const float* __restrict__ w, unsigned short* __restrict__ wb, long long n)
{
  long long i = ((long long)blockIdx.x * blockDim.x + threadIdx.x) * 8;
  if (i + 7 >= n) {
    if (i >= n) return;
    for (long long j = i; j < n; ++j) wb[j] = f2bf(w[j]);
    return;
  }
  f32x4 v0 = __builtin_nontemporal_load(reinterpret_cast<const f32x4*>(w + i));
  f32x4 v1 = __builtin_nontemporal_load(reinterpret_cast<const f32x4*>(w + i + 4));
  uint4 o;
  o.x = (unsigned)f2bf(v0[0]) | ((unsigned)f2bf(v0[1]) << 16);
  o.y = (unsigned)f2bf(v0[2]) | ((unsigned)f2bf(v0[3]) << 16);
  o.z = (unsigned)f2bf(v1[0]) | ((unsigned)f2bf(v1[1]) << 16);
  o.w = (unsigned)f2bf(v1[2]) | ((unsigned)f2bf(v1[3]) << 16);
  *reinterpret_cast<uint4*>(wb + i) = o;
}

// ---------- kernel 3: 256x256-tile ONE-BARRIER counted-lgkm GEMM + bias ------
// 8 waves (2M x 4N), BK=64, LDS dbuf (128 KiB).  Per K-tile:
//   BAR -> stage(t+1 -> buf d^1)  [buf d^1 provably dead: all waves did
//          lgkm-drain on tile t-1's reads before this BAR]
//       -> issue ALL 24 ds_reads of buf d (order al,bl,bh,ah)
//       -> sched_barrier(0)  [no MFMA hoists above; no read sinks below]
//       -> Q1 (compiler waits lgkmcnt(12)) -> Q2 (lgkm 8) -> Q3,Q4 (lgkm 0)
//       -> vmcnt(0)  [staging issued a full tile earlier: free]
// The bh/ah reads are serviced DURING Q1/Q2 MFMA -> LDS/MFMA overlap, killing
// the measured burst-drain convoy (~4900 cyc/tile across R4/R7/R9 schedules).
#define BM 256
#define BN 256
#define BK 64

#define MFMA16(a, b, c) __builtin_amdgcn_mfma_f32_16x16x32_bf16(a, b, c, 0, 0, 0)

__global__ __launch_bounds__(512, 2) void gemm256_bias(
    const unsigned short* __restrict__ A,   // [M][K] bf16 bits
    const unsigned short* __restrict__ B,   // [N][K] bf16 bits
    const float* __restrict__ bias,         // [N]
    float* __restrict__ C,                  // [M][N] fp32
    int M, int N, int K)
{
  __shared__ unsigned short lds[2][2][2][128 * 64];   // [dbuf][A/B][half] : 128 KiB

  const int tid  = threadIdx.x;
  const int lane = tid & 63;
  const int wid  = tid >> 6;       // 0..7
  const int wm   = wid >> 2;       // 0..1
  const int wn   = wid & 3;        // 0..3
  const int laneq = lane & 15;
  const int laneh = lane >> 4;
  const int lq7   = laneq & 7;

  // ---- super-tile remap for L3 temporal locality (R6: FETCH -23%) ----
  const int ntm = M / BM;
  const int ntn = N / BN;
  int tm, tn;
  if ((ntm & 15) == 0) {
    int rem = blockIdx.x;
    int str = 0, stc = 0, w = 16;
    for (;;) {
      int w2 = (ntn - stc * 16 < 16) ? (ntn - stc * 16) : 16;
      int sz = 16 * w2;
      if (rem < sz) { w = w2; break; }
      rem -= sz;
      ++stc;
      if (stc * 16 >= ntn) { stc = 0; ++str; }
    }
    tm = str * 16 + rem / w;
    tn = stc * 16 + rem % w;
  } else {
    tm = (int)blockIdx.x / ntn;
    tn = (int)blockIdx.x % ntn;
  }
  const size_t m0 = (size_t)tm * BM;
  const size_t n0 = (size_t)tn * BN;

  const int NT = K / BK;

  // swizzled 16B-slot indices for ks=0,1
  const int ss0 = (laneh ^ lq7);        // slot 0..7
  const int ss1 = ((4 + laneh) ^ lq7);

  // per-thread LDS read base offsets (bytes)
  const char* ldsb = (const char*)&lds[0][0][0][0];
  const int aOff = wm * 16384 + laneq * 128;
  const int bOff = 32768 + (wn >> 1) * 16384 + ((wn & 1) * 64 + laneq) * 128;

  // per-thread staging source pointers (computed once)
  const int c0 = tid, c1 = 512 + tid;
  const int r0 = c0 >> 3, sl0 = (c0 & 7) ^ (r0 & 7);
  const int r1 = c1 >> 3, sl1 = (c1 & 7) ^ (r1 & 7);
  const unsigned short* gA0 = A + (m0 + r0) * (size_t)K + sl0 * 8;
  const unsigned short* gA1 = A + (m0 + r1) * (size_t)K + sl1 * 8;
  const unsigned short* gB0 = B + (n0 + r0) * (size_t)K + sl0 * 8;
  const unsigned short* gB1 = B + (n0 + r1) * (size_t)K + sl1 * 8;
  const size_t hstep = (size_t)128 * K;   // +128 rows

  // per-thread staging LDS dest bases (bytes): + mat*32768 + h*16384 + l*8192
  char* dst0 = (char*)ldsb + wid * 1024;           // dbuf 0
  char* dst1 = dst0 + 65536;                       // dbuf 1

  f32x4 acc[8][4];
  #pragma unroll
  for (int i = 0; i < 8; i++)
    #pragma unroll
    for (int j = 0; j < 4; j++)
      acc[i][j] = (f32x4){0.f, 0.f, 0.f, 0.f};

  // stage one full 256x64 K-tile (A+B, both halves): 8 gld_lds16 / thread
  #define STAGETILE(kt, dstD)                                                \
    do {                                                                     \
      gld_lds16(gA0 + (size_t)(kt) * 64,          (dstD));                   \
      gld_lds16(gA1 + (size_t)(kt) * 64,          (dstD) + 8192);            \
      gld_lds16(gA0 + hstep + (size_t)(kt) * 64,  (dstD) + 16384);           \
      gld_lds16(gA1 + hstep + (size_t)(kt) * 64,  (dstD) + 16384 + 8192);    \
      gld_lds16(gB0 + (size_t)(kt) * 64,          (dstD) + 32768);           \
      gld_lds16(gB1 + (size_t)(kt) * 64,          (dstD) + 32768 + 8192);    \
      gld_lds16(gB0 + hstep + (size_t)(kt) * 64,  (dstD) + 49152);           \
      gld_lds16(gB1 + hstep + (size_t)(kt) * 64,  (dstD) + 49152 + 8192);    \
    } while (0)

  // ---- prologue: stage tile0 into dbuf0 ----
  STAGETILE(0, dst0);
  WAITVM(0);
  BAR();

  bf16x8 al[4][2], ah[4][2], bl[2][2], bh[2][2];

  for (int t = 0; t < NT; ++t) {
    const int d = t & 1;
    const char* aS0 = ldsb + (d << 16) + aOff + ss0 * 16;
    const char* aS1 = ldsb + (d << 16) + aOff + ss1 * 16;
    const char* bS0 = ldsb + (d << 16) + bOff + ss0 * 16;
    const char* bS1 = ldsb + (d << 16) + bOff + ss1 * 16;

    // ---- stage tile t+1 into the other buffer (dead since last BAR) ----
    if (t + 1 < NT) { char* dn = d ? dst0 : dst1; STAGETILE(t + 1, dn); }

    // ---- issue ALL 24 ds_reads up front: al(8), bl(4), bh(4), ah(8) ----
    #pragma unroll
    for (int mi = 0; mi < 4; ++mi) {
      al[mi][0] = *(const bf16x8*)(aS0 + mi * 2048);
      al[mi][1] = *(const bf16x8*)(aS1 + mi * 2048);
    }
    #pragma unroll
    for (int nj = 0; nj < 2; ++nj) {
      bl[nj][0] = *(const bf16x8*)(bS0 + nj * 2048);
      bl[nj][1] = *(const bf16x8*)(bS1 + nj * 2048);
    }
    #pragma unroll
    for (int nj = 0; nj < 2; ++nj) {
      bh[nj][0] = *(const bf16x8*)(bS0 + 4096 + nj * 2048);
      bh[nj][1] = *(const bf16x8*)(bS1 + 4096 + nj * 2048);
    }
    #pragma unroll
    for (int mi = 0; mi < 4; ++mi) {
      ah[mi][0] = *(const bf16x8*)(aS0 + 8192 + mi * 2048);
      ah[mi][1] = *(const bf16x8*)(aS1 + 8192 + mi * 2048);
    }
    SCHED0();   // fence: reads stay above, MFMAs stay below

    __builtin_amdgcn_s_setprio(1);
    // Q1: al x bl  (compiler waits lgkmcnt(12): bh+ah still in flight)
    #pragma unroll
    for (int mi = 0; mi < 4; ++mi)
      #pragma unroll
      for (int nj = 0; nj < 2; ++nj) {
        acc[mi][nj] = MFMA16(al[mi][0], bl[nj][0], acc[mi][nj]);
        acc[mi][nj] = MFMA16(al[mi][1], bl[nj][1], acc[mi][nj]);
      }
    SCHED0();
    // Q2: al x bh  (lgkmcnt(8): ah in flight)
    #pragma unroll
    for (int mi = 0; mi < 4; ++mi)
      #pragma unroll
      for (int nj = 0; nj < 2; ++nj) {
        acc[mi][2 + nj] = MFMA16(al[mi][0], bh[nj][0], acc[mi][2 + nj]);
        acc[mi][2 + nj] = MFMA16(al[mi][1], bh[nj][1], acc[mi][2 + nj]);
      }
    SCHED0();
    // Q3: ah x bh  (lgkmcnt(0))
    #pragma unroll
    for (int mi = 0; mi < 4; ++mi)
      #pragma unroll
      for (int nj = 0; nj < 2; ++nj) {
        acc[4 + mi][2 + nj] = MFMA16(ah[mi][0], bh[nj][0], acc[4 + mi][2 + nj]);
        acc[4 + mi][2 + nj] = MFMA16(ah[mi][1], bh[nj][1], acc[4 + mi][2 + nj]);
      }
    // Q4: ah x bl
    #pragma unroll
    for (int mi = 0; mi < 4; ++mi)
      #pragma unroll
      for (int nj = 0; nj < 2; ++nj) {
        acc[4 + mi][nj] = MFMA16(ah[mi][0], bl[nj][0], acc[4 + mi][nj]);
        acc[4 + mi][nj] = MFMA16(ah[mi][1], bl[nj][1], acc[4 + mi][nj]);
      }
    __builtin_amdgcn_s_setprio(0);

    // tile t+1's staging (issued a full tile ago) must be in LDS before
    // anyone reads it next iteration
    WAITVM(0);
    BAR();
  }
  #undef STAGETILE

  // ---- epilogue: C = acc + bias (non-temporal: don't churn L3) ----
  // C/D layout: col = lane&15, row = (lane>>4)*4 + reg
  #pragma unroll
  for (int nj = 0; nj < 4; ++nj) {
    int col = (int)n0 + wn * 64 + nj * 16 + laneq;
    float bv = bias[col];
    #pragma unroll
    for (int mi = 0; mi < 8; ++mi) {
      size_t row = m0 + wm * 128 + mi * 16 + laneh * 4;
      float* cp = C + row * (size_t)N + col;
      #pragma unroll
      for (int r = 0; r < 4; ++r)
        __builtin_nontemporal_store(acc[mi][nj][r] + bv, cp + (size_t)r * N);
    }
  }
}

// ---------- launcher ----------
extern "C" void kernel_launch(void* const* d_in, const int* in_sizes, int n_in,
                              void* d_out, int out_size, void* d_ws, size_t ws_size,
                              hipStream_t stream) {
  const float* x    = (const float*)d_in[0];
  const float* w    = (const float*)d_in[1];
  const float* bias = (const float*)d_in[2];
  float* out = (float*)d_out;

  const long long xN = in_sizes[0];          // M*K
  const long long wN = in_sizes[1];          // N*K
  const int N = in_sizes[2];
  const int K = (int)(wN / N);
  const int M = (int)(xN / K);

  unsigned short* xb = (unsigned short*)d_ws;          // M*K bf16
  unsigned short* wb = xb + xN;                        // N*K bf16

  long long ngroups = xN / 128;
  long long qblocks = (ngroups + 3) / 4;
  quant_x_kernel<<<(int)qblocks, 256, 0, stream>>>(x, xb, ngroups);

  long long cblocks = (wN + 2047) / 2048;
  cvt_w_kernel<<<(int)cblocks, 256, 0, stream>>>(w, wb, wN);

  int grid = (M / BM) * (N / BN);
  gemm256_bias<<<grid, 512, 0, stream>>>(xb, wb, bias, out, M, N, K);
}